// Round 1
// baseline (18587.230 us; speedup 1.0000x reference)
//
#include <hip/hip_runtime.h>
#include <stdint.h>
#include <math.h>

// ---------------------------------------------------------------------------
// LSTMAcceptor on MI355X — round 1 baseline.
// Design notes:
//  * Recurrence is inherently sequential (512 steps). Round-1 uses one kernel
//    launch per step: the kernel boundary provides the grid-wide barrier and
//    cross-XCD coherence with zero correctness risk. (Persistent cooperative
//    kernel is the planned round-2+ upgrade once counters confirm overhead.)
//  * No fp32 MFMA on CDNA4 -> split-bf16 trick for fp32-class accuracy:
//      w = w_hi + w_lo (both bf16), h = h_hi + h_lo
//      w*h ~= w_hi*h_hi + w_hi*h_lo + w_lo*h_hi   (drop lo*lo, ~2^-18 rel err)
//    Weights pre-split once (prep kernel, ws). h written pre-split each step.
//  * Input projection (emb @ W_ih^T) is FUSED into the step kernel (K=1536)
//    to avoid a 256-512MB x_proj workspace; emb rows are split on the fly.
//  * lengths input is UNUSED by the reference; padding_idx=0 -> emb row 0 = 0.
//  * ws layout (~24.8 MB): c | h_hi[2] | h_lo[2] | bias | WihHi|WihLo|WhhHi|WhhLo
// ---------------------------------------------------------------------------

#define HID  1024
#define EMBD 512
#define NB   64
#define NT   512
#define G4   4096   // 4*HID

using bf16x8  = __attribute__((ext_vector_type(8))) __bf16;
using ushort8 = __attribute__((ext_vector_type(8))) unsigned short;
using f32x4   = __attribute__((ext_vector_type(4))) float;

__device__ __forceinline__ unsigned short f2bf(float f) {
  // round-to-nearest-even float -> bf16 (no NaN handling needed here)
  unsigned u = __float_as_uint(f);
  u += 0x7fffu + ((u >> 16) & 1u);
  return (unsigned short)(u >> 16);
}
__device__ __forceinline__ float bf2f(unsigned short s) {
  return __uint_as_float(((unsigned)s) << 16);
}

// ---------------------------------------------------------------------------
// prep: split fp32 weights into hi/lo bf16 pair (one-time, off critical path)
__global__ void prep_weights(const float* __restrict__ Wih, const float* __restrict__ Whh,
                             unsigned short* __restrict__ WihHi, unsigned short* __restrict__ WihLo,
                             unsigned short* __restrict__ WhhHi, unsigned short* __restrict__ WhhLo) {
  const int NIH = G4 * EMBD;                 // 2097152
  int idx = blockIdx.x * 256 + threadIdx.x;  // grid sized exactly NIH+NHH
  if (idx < NIH) {
    float v = Wih[idx];
    unsigned short hb = f2bf(v);
    WihHi[idx] = hb;
    WihLo[idx] = f2bf(v - bf2f(hb));
  } else {
    int k = idx - NIH;                       // < 4194304
    float v = Whh[k];
    unsigned short hb = f2bf(v);
    WhhHi[k] = hb;
    WhhLo[k] = f2bf(v - bf2f(hb));
  }
}

__global__ void prep_bias(const float* __restrict__ bih, const float* __restrict__ bhh,
                          float* __restrict__ bias) {
  int i = blockIdx.x * 256 + threadIdx.x;
  if (i < G4) bias[i] = bih[i] + bhh[i];
}

// ws is re-poisoned to 0xAA before every timed call -> must zero state each call
__global__ void zero_state(float* __restrict__ c,
                           unsigned short* __restrict__ hHi0,
                           unsigned short* __restrict__ hLo0) {
  int i = blockIdx.x * 256 + threadIdx.x;    // grid covers 65536 exactly
  c[i] = 0.f;
  hHi0[i] = 0;
  hLo0[i] = 0;
}

// ---------------------------------------------------------------------------
// One LSTM timestep. Grid: 256 WGs = 2 batch-tiles(32 rows) x 128 gate-tiles
// (8 hidden units -> 32 gate rows: i,f,g,o co-located for the cell update).
// Block: 256 threads = 4 waves, 2x2 grid of 16x16x32 bf16 MFMA tiles, K=1536.
__global__ __launch_bounds__(256) void lstm_step(
    const int* __restrict__ x, const float* __restrict__ emb,
    const unsigned short* __restrict__ WihHi, const unsigned short* __restrict__ WihLo,
    const unsigned short* __restrict__ WhhHi, const unsigned short* __restrict__ WhhLo,
    const float* __restrict__ bias,
    const unsigned short* __restrict__ hHiIn, const unsigned short* __restrict__ hLoIn,
    unsigned short* __restrict__ hHiOut, unsigned short* __restrict__ hLoOut,
    float* __restrict__ c, int t) {
  const int wg   = blockIdx.x;
  const int bt   = wg >> 7;         // 0..1   batch tile (32 rows)
  const int gt   = wg & 127;        // 0..127 hidden-unit tile (8 units)
  const int tid  = threadIdx.x;
  const int wave = tid >> 6;
  const int lane = tid & 63;
  const int msub = wave >> 1, nsub = wave & 1;
  const int l15  = lane & 15;
  const int kg8  = (lane >> 4) * 8;

  const int mrow = bt * 32 + msub * 16 + l15;               // batch row 0..63
  const int nloc = nsub * 16 + l15;                         // 0..31
  const int grow = (nloc >> 3) * HID + gt * 8 + (nloc & 7); // gate row 0..4095

  f32x4 acc = {0.f, 0.f, 0.f, 0.f};

  const int  tok = x[mrow * NT + t];
  const bool pad = (tok == 0);
  const float* erow = emb + (size_t)tok * EMBD;

  // ---- input-projection part of the gates: K = 0..511 (emb row, split on the fly)
  {
    const unsigned short* bH = WihHi + (size_t)grow * EMBD;
    const unsigned short* bL = WihLo + (size_t)grow * EMBD;
#pragma unroll 4
    for (int kc = 0; kc < 16; ++kc) {
      const int k0 = kc * 32 + kg8;
      ushort8 ah, al;
#pragma unroll
      for (int i = 0; i < 8; ++i) {
        float v = pad ? 0.f : erow[k0 + i];
        unsigned short hb = f2bf(v);
        ah[i] = hb;
        al[i] = f2bf(v - bf2f(hb));
      }
      bf16x8 aH = __builtin_bit_cast(bf16x8, ah);
      bf16x8 aL = __builtin_bit_cast(bf16x8, al);
      bf16x8 bHf = *(const bf16x8*)(bH + k0);
      bf16x8 bLf = *(const bf16x8*)(bL + k0);
      acc = __builtin_amdgcn_mfma_f32_16x16x32_bf16(aH, bHf, acc, 0, 0, 0);
      acc = __builtin_amdgcn_mfma_f32_16x16x32_bf16(aH, bLf, acc, 0, 0, 0);
      acc = __builtin_amdgcn_mfma_f32_16x16x32_bf16(aL, bHf, acc, 0, 0, 0);
    }
  }
  // ---- recurrent part: K = 0..1023 (h pre-split by previous step's epilogue)
  {
    const unsigned short* aHp = hHiIn + (size_t)mrow * HID;
    const unsigned short* aLp = hLoIn + (size_t)mrow * HID;
    const unsigned short* bHp = WhhHi + (size_t)grow * HID;
    const unsigned short* bLp = WhhLo + (size_t)grow * HID;
#pragma unroll 4
    for (int kc = 0; kc < 32; ++kc) {
      const int k0 = kc * 32 + kg8;
      bf16x8 aHf = *(const bf16x8*)(aHp + k0);
      bf16x8 aLf = *(const bf16x8*)(aLp + k0);
      bf16x8 bHf = *(const bf16x8*)(bHp + k0);
      bf16x8 bLf = *(const bf16x8*)(bLp + k0);
      acc = __builtin_amdgcn_mfma_f32_16x16x32_bf16(aHf, bHf, acc, 0, 0, 0);
      acc = __builtin_amdgcn_mfma_f32_16x16x32_bf16(aHf, bLf, acc, 0, 0, 0);
      acc = __builtin_amdgcn_mfma_f32_16x16x32_bf16(aLf, bHf, acc, 0, 0, 0);
    }
  }

  // ---- exchange gate tiles across waves (C/D layout: m=(lane>>4)*4+r, n=lane&15)
  __shared__ float gl[32][33];
  const int mb = msub * 16 + (lane >> 4) * 4;
#pragma unroll
  for (int r = 0; r < 4; ++r) gl[nloc][mb + r] = acc[r];
  __syncthreads();

  // ---- cell update: 256 threads = 32 batch-local x 8 hidden-local
  const int bl = tid >> 3;  // 0..31
  const int j  = tid & 7;   // 0..7
  const int hu = gt * 8 + j;
  const int bglob = bt * 32 + bl;
  const int cidx  = bglob * HID + hu;

  float gi = gl[0 + j][bl]  + bias[hu];
  float gf = gl[8 + j][bl]  + bias[HID + hu];
  float gg = gl[16 + j][bl] + bias[2 * HID + hu];
  float go = gl[24 + j][bl] + bias[3 * HID + hu];

  float si = 1.f / (1.f + expf(-gi));
  float sf = 1.f / (1.f + expf(-gf));
  float so = 1.f / (1.f + expf(-go));
  float tg = tanhf(gg);
  float cn = sf * c[cidx] + si * tg;
  float hn = so * tanhf(cn);
  c[cidx] = cn;
  unsigned short hb = f2bf(hn);
  hHiOut[cidx] = hb;
  hLoOut[cidx] = f2bf(hn - bf2f(hb));
}

// ---------------------------------------------------------------------------
// Head: out[b] = W2 @ relu(W1 @ h_T[b] + b1) + b2.  64 WGs (one per batch row).
__global__ __launch_bounds__(256) void head_kernel(
    const unsigned short* __restrict__ hHi, const unsigned short* __restrict__ hLo,
    const float* __restrict__ W1, const float* __restrict__ b1,
    const float* __restrict__ W2, const float* __restrict__ b2,
    float* __restrict__ out) {
  const int b = blockIdx.x;
  const int tid = threadIdx.x;
  const int u = tid >> 2, q = tid & 3;
  const int base = b * HID;

  float s = 0.f;
  const int k0 = q * 256;
#pragma unroll 4
  for (int k = k0; k < k0 + 256; ++k) {
    float hv = bf2f(hHi[base + k]) + bf2f(hLo[base + k]);
    s += W1[u * HID + k] * hv;
  }
  __shared__ float red[64][4];
  __shared__ float hl[64];
  red[u][q] = s;
  __syncthreads();
  if (tid < 64) {
    float v = red[tid][0] + red[tid][1] + red[tid][2] + red[tid][3] + b1[tid];
    hl[tid] = v > 0.f ? v : 0.f;
  }
  __syncthreads();
  if (tid < 64) {  // single wave: 64-lane reduce
    float v = hl[tid] * W2[tid];
#pragma unroll
    for (int off = 32; off; off >>= 1) v += __shfl_down(v, off);
    if (tid == 0) out[b] = v + b2[0];
  }
}

// ---------------------------------------------------------------------------
extern "C" void kernel_launch(void* const* d_in, const int* in_sizes, int n_in,
                              void* d_out, int out_size, void* d_ws, size_t ws_size,
                              hipStream_t stream) {
  const int*   x   = (const int*)d_in[0];
  // d_in[1] = lengths : UNUSED by the reference
  const float* emb = (const float*)d_in[2];
  const float* Wih = (const float*)d_in[3];
  const float* bih = (const float*)d_in[4];
  const float* Whh = (const float*)d_in[5];
  const float* bhh = (const float*)d_in[6];
  const float* W1  = (const float*)d_in[7];
  const float* b1  = (const float*)d_in[8];
  const float* W2  = (const float*)d_in[9];
  const float* b2  = (const float*)d_in[10];
  float* out = (float*)d_out;

  // ---- workspace layout (bytes) ----
  char* ws = (char*)d_ws;
  float*          c     = (float*)(ws + 0);                       // 256 KB
  unsigned short* hHi   = (unsigned short*)(ws + (256 << 10));    // 2 x 128 KB (ping-pong)
  unsigned short* hLo   = (unsigned short*)(ws + (512 << 10));    // 2 x 128 KB
  float*          bias  = (float*)(ws + (768 << 10));             // 16 KB
  unsigned short* WihHi = (unsigned short*)(ws + (784 << 10));    // 4 MB
  unsigned short* WihLo = WihHi + (size_t)G4 * EMBD;              // 4 MB
  unsigned short* WhhHi = WihLo + (size_t)G4 * EMBD;              // 8 MB
  unsigned short* WhhLo = WhhHi + (size_t)G4 * HID;               // 8 MB
  const size_t ws_needed = (784ull << 10) + 2ull * ((size_t)G4 * EMBD + (size_t)G4 * HID) * 2ull * 2ull;
  if (ws_size < ws_needed) return;  // avoid OOB corruption; visible as wrong output

  zero_state<<<256, 256, 0, stream>>>(c, hHi, hLo);
  prep_bias<<<16, 256, 0, stream>>>(bih, bhh, bias);
  prep_weights<<<(G4 * EMBD + G4 * HID) / 256, 256, 0, stream>>>(Wih, Whh, WihHi, WihLo, WhhHi, WhhLo);

  for (int t = 0; t < NT; ++t) {
    const unsigned short* hiIn = hHi + (size_t)(t & 1) * (NB * HID);
    const unsigned short* loIn = hLo + (size_t)(t & 1) * (NB * HID);
    unsigned short* hiOut = hHi + (size_t)((t + 1) & 1) * (NB * HID);
    unsigned short* loOut = hLo + (size_t)((t + 1) & 1) * (NB * HID);
    lstm_step<<<256, 256, 0, stream>>>(x, emb, WihHi, WihLo, WhhHi, WhhLo, bias,
                                       hiIn, loIn, hiOut, loOut, c, t);
  }
  // after t=511 the freshest h is in buffer ((512)&1)==0
  head_kernel<<<64, 256, 0, stream>>>(hHi, hLo, W1, b1, W2, b2, out);
}